// Round 1
// baseline (87850.714 us; speedup 1.0000x reference)
//
#include <hip/hip_runtime.h>
#include <math.h>

#define T_LEN 128
#define BATCH 64
#define IND   512
#define HDIM  256
#define NS    8
#define H4    1024
#define K1    512
#define NBLK  256
#define NTHR  512

// ws offsets (in floats)
#define OFF_CTRL 0
#define OFF_QPRE 2048
#define OFF_KPRE (OFF_QPRE + BATCH*HDIM)      // 18432
#define OFF_M    (OFF_KPRE + BATCH*NS*HDIM)   // 149504
#define OFF_H    (OFF_M + BATCH*NS*HDIM)      // 280576
#define OFF_Z1   (OFF_H + BATCH*HDIM)         // 296960
#define OFF_Z2   (OFF_Z1 + BATCH*H4)          // 362496
#define OFF_CP   (OFF_Z2 + BATCH*H4)          // 428032
// total ~428544 floats = 1.72 MB of ws

__device__ __forceinline__ float wred_sum(float v) {
#pragma unroll
  for (int off = 32; off > 0; off >>= 1) v += __shfl_xor(v, off, 64);
  return v;
}

// two-level grid barrier: 8 groups of 32 blocks -> root counter -> generation
__device__ __forceinline__ void gsync(int* ctrl, int target) {
  __syncthreads();
  if (threadIdx.x == 0) {
    int g = blockIdx.x >> 5;
    int prev = __hip_atomic_fetch_add(ctrl + g * 32, 1, __ATOMIC_ACQ_REL, __HIP_MEMORY_SCOPE_AGENT);
    if (prev == 31) {
      int p2 = __hip_atomic_fetch_add(ctrl + 1024, 1, __ATOMIC_ACQ_REL, __HIP_MEMORY_SCOPE_AGENT);
      if (p2 == 7) {
#pragma unroll
        for (int q = 0; q < 8; ++q)
          __hip_atomic_store(ctrl + q * 32, 0, __ATOMIC_RELAXED, __HIP_MEMORY_SCOPE_AGENT);
        __hip_atomic_store(ctrl + 1024, 0, __ATOMIC_RELAXED, __HIP_MEMORY_SCOPE_AGENT);
        __hip_atomic_store(ctrl + 1040, target, __ATOMIC_RELEASE, __HIP_MEMORY_SCOPE_AGENT);
      }
    }
    while (__hip_atomic_load(ctrl + 1040, __ATOMIC_ACQUIRE, __HIP_MEMORY_SCOPE_AGENT) < target) {
      __builtin_amdgcn_s_sleep(1);
    }
  }
  __syncthreads();
}

extern "C" __global__ __launch_bounds__(256) void xp_kernel(
    const float* __restrict__ X, const float* __restrict__ Wp, const float* __restrict__ bp,
    const float* __restrict__ lns, const float* __restrict__ lnb, float* __restrict__ out_xp)
{
  __shared__ float Xs[8 * IND];
  __shared__ float Ys[8 * HDIM];
  const int tid = threadIdx.x;
  const size_t base = (size_t)blockIdx.x * 8;          // 8 (t,b) rows per block
  const float* Xb = X + base * IND;
  for (int e = tid; e < 8 * IND / 4; e += 256) ((float4*)Xs)[e] = ((const float4*)Xb)[e];
  __syncthreads();
  float acc[8];
#pragma unroll
  for (int r = 0; r < 8; ++r) acc[r] = 0.f;
  for (int k = 0; k < IND; ++k) {
    float wv = Wp[k * HDIM + tid];
#pragma unroll
    for (int r = 0; r < 8; ++r) acc[r] += Xs[r * IND + k] * wv;
  }
  float bpv = bp[tid];
#pragma unroll
  for (int r = 0; r < 8; ++r) Ys[r * HDIM + tid] = acc[r] + bpv;
  __syncthreads();
  int w = tid >> 6, lane = tid & 63;
  for (int rr = 0; rr < 2; ++rr) {
    int r = w * 2 + rr;
    float v[4]; float s1 = 0.f, s2 = 0.f;
#pragma unroll
    for (int e = 0; e < 4; ++e) { v[e] = Ys[r * HDIM + lane + 64 * e]; s1 += v[e]; s2 += v[e] * v[e]; }
    s1 = wred_sum(s1); s2 = wred_sum(s2);
    float m = s1 / 256.f;
    float iv = rsqrtf(s2 / 256.f - m * m + 1e-5f);
#pragma unroll
    for (int e = 0; e < 4; ++e) {
      int hd = lane + 64 * e;
      out_xp[(base + r) * HDIM + hd] = tanhf((v[e] - m) * iv * lns[hd] + lnb[hd]);
    }
  }
}

extern "C" __global__ void init_ctrl(int* ctrl) {
  int t = blockIdx.x * blockDim.x + threadIdx.x;
  if (t < 2048) ctrl[t] = 0;
}

extern "C" __global__ __launch_bounds__(NTHR, 2) void omr_main(
    const float* __restrict__ Xp,
    const float* __restrict__ Wq, const float* __restrict__ bq,
    const float* __restrict__ lnqs, const float* __restrict__ lnqb,
    const float* __restrict__ Wk, const float* __restrict__ bk,
    const float* __restrict__ lnks, const float* __restrict__ lnkb,
    const float* __restrict__ Wbeta, const float* __restrict__ bbeta,
    const float* __restrict__ W1, const float* __restrict__ b1,
    const float* __restrict__ W2, const float* __restrict__ b2,
    const float* __restrict__ lns, const float* __restrict__ lnb,
    float* __restrict__ mem_out, float* __restrict__ probs_out, float* __restrict__ ws)
{
  const int j = blockIdx.x;
  const int tid = threadIdx.x;
  const int cg = j & 63, rg = j >> 6;    // z-stage tiling: 16 cols, 16 rows per block
  const int c0 = cg * 16, r0 = rg * 16;
  const int sc = j & 31, sr = j >> 5;    // S1a tiling: 8 cols, 72 rows per block
  const int q0 = sc * 8;

  __shared__ float W1s[K1 * 16];         // 32 KB: W1[:, c0:c0+16]
  __shared__ float W2s[H4 * 16];         // 64 KB: W2[:, c0:c0+16]
  __shared__ float Wqs[HDIM * 8];        // 8 KB
  __shared__ float Wks[HDIM * 8];        // 8 KB
  __shared__ float Wbs[HDIM];
  __shared__ float LNQS[HDIM], LNQB[HDIM], LNKS[HDIM], LNKB[HDIM], LNS[HDIM], LNB[HDIM];
  __shared__ float sbuf[NTHR];
  __shared__ float qls[HDIM];
  __shared__ float betas[NS], cps[NS], rcps[NS];
  __shared__ float b1s[16], b2s[16], bqs[8], bks[8];
  __shared__ float part1[8], part2[8];
  __shared__ float stat2[2];

  for (int e = tid; e < K1 * 4; e += NTHR) {
    int k = e >> 2, cq = e & 3;
    ((float4*)W1s)[e] = *(const float4*)(W1 + (size_t)k * H4 + c0 + cq * 4);
  }
  for (int e = tid; e < H4 * 4; e += NTHR) {
    int k = e >> 2, cq = e & 3;
    ((float4*)W2s)[e] = *(const float4*)(W2 + (size_t)k * H4 + c0 + cq * 4);
  }
  for (int e = tid; e < HDIM * 2; e += NTHR) {
    int k = e >> 1, hh = e & 1;
    ((float4*)Wqs)[e] = *(const float4*)(Wq + k * HDIM + q0 + hh * 4);
    ((float4*)Wks)[e] = *(const float4*)(Wk + k * HDIM + q0 + hh * 4);
  }
  if (tid < HDIM) {
    Wbs[tid] = Wbeta[tid];
    LNQS[tid] = lnqs[tid]; LNQB[tid] = lnqb[tid];
    LNKS[tid] = lnks[tid]; LNKB[tid] = lnkb[tid];
    LNS[tid]  = lns[tid];  LNB[tid]  = lnb[tid];
  }
  if (tid < 16) { b1s[tid] = b1[c0 + tid]; b2s[tid] = b2[c0 + tid]; }
  if (tid < 8)  { bqs[tid] = bq[q0 + tid]; bks[tid] = bk[q0 + tid]; }

  int* ctrl = (int*)ws;
  int bar = 0;

  // ---- t = 0 init: M = 0, memories[0][b][i][:] = Xp[0][b][:], probs[0] = 0 ----
  {
    int e = j * 512 + tid;                // covers 131072 elements
    ws[OFF_M + e] = 0.0f;
    int b = e >> 11, hd = e & 255;
    mem_out[e] = Xp[b * HDIM + hd];
    if (j == 0) probs_out[tid] = 0.0f;    // 512 = BATCH*NS
  }
  gsync(ctrl, ++bar);

  for (int t = 1; t < T_LEN; ++t) {
    const float* xp_t = Xp + (size_t)t * BATCH * HDIM;
    const float* mem_prev = mem_out + (size_t)(t - 1) * BATCH * NS * HDIM;

    // ---- S1a: qpre = Xp[t]@Wq + bq ; kpre = cM@Wk + bk (pre-LN) ----
    for (int o = tid; o < 576; o += NTHR) {
      int lr = o >> 3, c = o & 7;
      int row = sr * 72 + lr;            // 0..63 q-rows, 64..575 k-rows
      const float* A; const float* Wcol; float bias;
      if (row < 64) { A = xp_t + row * HDIM; Wcol = Wqs + c; bias = bqs[c]; }
      else { int kr = row - 64; A = mem_prev + kr * HDIM; Wcol = Wks + c; bias = bks[c]; }
      float a0 = 0, a1 = 0, a2 = 0, a3 = 0;
      for (int k = 0; k < HDIM; k += 4) {
        float4 av = *(const float4*)(A + k);
        a0 += av.x * Wcol[(k + 0) * 8];
        a1 += av.y * Wcol[(k + 1) * 8];
        a2 += av.z * Wcol[(k + 2) * 8];
        a3 += av.w * Wcol[(k + 3) * 8];
      }
      float val = (a0 + a1) + (a2 + a3) + bias;
      if (row < 64) ws[OFF_QPRE + row * HDIM + q0 + c] = val;
      else          ws[OFF_KPRE + (row - 64) * HDIM + q0 + c] = val;
    }
    gsync(ctrl, ++bar);

    // ---- S1b: LN(q), LN(k), beta, softmax+mask -> p/cp/rcp, Mn, h0 (64 blocks) ----
    if (j < 64) {
      const int b = j;
      float qv = 0.f;
      if (tid < HDIM) { qv = ws[OFF_QPRE + b * HDIM + tid]; sbuf[tid] = qv; }
      float s1 = (tid < HDIM) ? qv : 0.f;
      float s2 = (tid < HDIM) ? qv * qv : 0.f;
      s1 = wred_sum(s1); s2 = wred_sum(s2);
      int w = tid >> 6, lane = tid & 63;
      if (lane == 0) { part1[w] = s1; part2[w] = s2; }
      __syncthreads();
      if (tid == 0) {
        float su = part1[0] + part1[1] + part1[2] + part1[3];
        float sq = part2[0] + part2[1] + part2[2] + part2[3];
        float m = su / 256.f;
        stat2[0] = m; stat2[1] = rsqrtf(sq / 256.f - m * m + 1e-5f);
      }
      __syncthreads();
      if (tid < HDIM) qls[tid] = (sbuf[tid] - stat2[0]) * stat2[1] * LNQS[tid] + LNQB[tid];
      __syncthreads();
      {
        int i = w;                        // wave index == slot
        float kv[4]; float ks1 = 0.f, ks2 = 0.f;
#pragma unroll
        for (int e = 0; e < 4; ++e) {
          kv[e] = ws[OFF_KPRE + (b * NS + i) * HDIM + lane + 64 * e];
          ks1 += kv[e]; ks2 += kv[e] * kv[e];
        }
        ks1 = wred_sum(ks1); ks2 = wred_sum(ks2);
        float km = ks1 / 256.f;
        float kiv = rsqrtf(ks2 / 256.f - km * km + 1e-5f);
        float bpp = 0.f;
#pragma unroll
        for (int e = 0; e < 4; ++e) {
          int hd = lane + 64 * e;
          float kl = (kv[e] - km) * kiv * LNKS[hd] + LNKB[hd];
          float rv = fmaxf(qls[hd] + kl, 0.f);
          bpp += rv * Wbs[hd];
        }
        bpp = wred_sum(bpp);
        if (lane == 0) betas[i] = (bpp + bbeta[0]) * 0.0625f;
      }
      __syncthreads();
      if (tid == 0) {
        float pp[8], pcp[8];
        float run = 0.f;
#pragma unroll
        for (int i = 0; i < 8; ++i) {
          pp[i] = probs_out[((size_t)(t - 1) * BATCH + b) * NS + i];
          run += pp[i]; pcp[i] = run;
        }
        float bmax = betas[0];
#pragma unroll
        for (int i = 1; i < 8; ++i) bmax = fmaxf(bmax, betas[i]);
        float xm[8]; float ssum = 0.f;
#pragma unroll
        for (int i = 0; i < 8; ++i) {
          float mi;
          if (i < 7) { float cv = pcp[i + 1]; mi = (cv < 1e-5f) ? 0.f : cv; }
          else mi = 1.f;
          float xv = expf(betas[i] - bmax);
          xm[i] = xv * mi; ssum += fabsf(xm[i]);
        }
        float denom = fmaxf(ssum, 1e-12f);
        float run2 = 0.f; float pn[8];
#pragma unroll
        for (int i = 0; i < 8; ++i) {
          pn[i] = xm[i] / denom; run2 += pn[i];
          cps[i] = run2;
          ws[OFF_CP + b * NS + i] = run2;
          probs_out[((size_t)t * BATCH + b) * NS + i] = pn[i];
        }
        float run3 = 0.f;
#pragma unroll
        for (int i = 7; i >= 0; --i) { run3 += pn[i]; rcps[i] = run3; }
      }
      __syncthreads();
      for (int e = tid; e < NS * HDIM; e += NTHR) {
        int i = e >> 8, hd = e & 255;
        int idx = (b * NS + i) * HDIM + hd;
        float r = rcps[i];
        float mo = ws[OFF_M + idx];
        float cm = mem_prev[idx];
        ws[OFF_M + idx] = mo * (1.f - r) + cm * r;
      }
      if (tid < HDIM) ws[OFF_H + b * HDIM + tid] = xp_t[b * HDIM + tid];
    }
    gsync(ctrl, ++bar);

    // ---- 8 sequential cells ----
    for (int i = 0; i < NS; ++i) {
      // S2: z1 = relu(cat(h, Mn_i) @ W1 + b1)  (split-K over 2 halves)
      {
        int s = tid >> 8, u = tid & 255;
        int r = u >> 4, c = u & 15;
        const float* A = (s == 0) ? (ws + OFF_H + (r0 + r) * HDIM)
                                  : (ws + OFF_M + ((r0 + r) * NS + i) * HDIM);
        const float* Wcol = W1s + s * 256 * 16 + c;
        float a0 = 0, a1 = 0, a2 = 0, a3 = 0;
        for (int k = 0; k < 256; k += 4) {
          float4 av = *(const float4*)(A + k);
          a0 += av.x * Wcol[(k + 0) * 16];
          a1 += av.y * Wcol[(k + 1) * 16];
          a2 += av.z * Wcol[(k + 2) * 16];
          a3 += av.w * Wcol[(k + 3) * 16];
        }
        sbuf[tid] = (a0 + a1) + (a2 + a3);
      }
      __syncthreads();
      if (tid < 256) {
        int r = tid >> 4, c = tid & 15;
        float v = sbuf[tid] + sbuf[tid + 256] + b1s[c];
        ws[OFF_Z1 + (r0 + r) * H4 + c0 + c] = fmaxf(v, 0.f);
      }
      gsync(ctrl, ++bar);

      // S3: z2 = z1r @ W2 + b2
      {
        int s = tid >> 8, u = tid & 255;
        int r = u >> 4, c = u & 15;
        const float* A = ws + OFF_Z1 + (r0 + r) * H4 + s * 512;
        const float* Wcol = W2s + s * 512 * 16 + c;
        float a0 = 0, a1 = 0, a2 = 0, a3 = 0;
        for (int k = 0; k < 512; k += 4) {
          float4 av = *(const float4*)(A + k);
          a0 += av.x * Wcol[(k + 0) * 16];
          a1 += av.y * Wcol[(k + 1) * 16];
          a2 += av.z * Wcol[(k + 2) * 16];
          a3 += av.w * Wcol[(k + 3) * 16];
        }
        sbuf[tid] = (a0 + a1) + (a2 + a3);
      }
      __syncthreads();
      if (tid < 256) {
        int r = tid >> 4, c = tid & 15;
        float v = sbuf[tid] + sbuf[tid + 256] + b2s[c];
        ws[OFF_Z2 + (r0 + r) * H4 + c0 + c] = v;
      }
      gsync(ctrl, ++bar);

      // S4: gates + LN(c) + tanh + h update (4 blocks per batch row)
      {
        const int b = j >> 2, part = j & 3;
        float cv = 0.f;
        if (tid < HDIM) cv = ws[OFF_Z2 + b * H4 + 768 + tid];
        float s1 = (tid < HDIM) ? cv : 0.f;
        float s2v = (tid < HDIM) ? cv * cv : 0.f;
        s1 = wred_sum(s1); s2v = wred_sum(s2v);
        int w = tid >> 6;
        if ((tid & 63) == 0) { part1[w] = s1; part2[w] = s2v; }
        __syncthreads();
        if (tid == 0) {
          float su = part1[0] + part1[1] + part1[2] + part1[3];
          float sq = part2[0] + part2[1] + part2[2] + part2[3];
          float m = su / 256.f;
          stat2[0] = m; stat2[1] = rsqrtf(sq / 256.f - m * m + 1e-5f);
        }
        __syncthreads();
        if (tid < 64) {
          int hd = part * 64 + tid;
          const float* zrow = ws + OFF_Z2 + b * H4;
          float z0 = zrow[3 * hd], z1v = zrow[3 * hd + 1], z2g = zrow[3 * hd + 2];
          float gm = fmaxf(z0, fmaxf(z1v, z2g));
          float e0 = expf(z0 - gm), e1 = expf(z1v - gm), e2 = expf(z2g - gm);
          float ginv = 1.f / (e0 + e1 + e2);
          float cvh = zrow[768 + hd];
          float act = tanhf((cvh - stat2[0]) * stat2[1] * LNS[hd] + LNB[hd]);
          float vi = ws[OFF_H + b * HDIM + hd];
          float hi = ws[OFF_M + (b * NS + i) * HDIM + hd];
          float hc = (e0 * vi + e1 * hi + e2 * act) * ginv;
          float cpi = ws[OFF_CP + b * NS + i];
          float hn = xp_t[b * HDIM + hd] * (1.f - cpi) + hc * cpi;
          ws[OFF_H + b * HDIM + hd] = hn;
          mem_out[((size_t)(t * BATCH + b) * NS + i) * HDIM + hd] = hn;
        }
      }
      gsync(ctrl, ++bar);
    }
  }
}

extern "C" void kernel_launch(void* const* d_in, const int* in_sizes, int n_in,
                              void* d_out, int out_size, void* d_ws, size_t ws_size,
                              hipStream_t stream) {
  (void)in_sizes; (void)n_in; (void)out_size; (void)ws_size;
  const float* X     = (const float*)d_in[0];
  const float* Wp    = (const float*)d_in[3];
  const float* bp    = (const float*)d_in[4];
  const float* lns   = (const float*)d_in[5];
  const float* lnb   = (const float*)d_in[6];
  const float* Wq    = (const float*)d_in[7];
  const float* bq    = (const float*)d_in[8];
  const float* lnqs  = (const float*)d_in[9];
  const float* lnqb  = (const float*)d_in[10];
  const float* Wk    = (const float*)d_in[11];
  const float* bk    = (const float*)d_in[12];
  const float* lnks  = (const float*)d_in[13];
  const float* lnkb  = (const float*)d_in[14];
  const float* Wbeta = (const float*)d_in[15];
  const float* bbeta = (const float*)d_in[16];
  const float* W1    = (const float*)d_in[17];
  const float* b1    = (const float*)d_in[18];
  const float* W2    = (const float*)d_in[19];
  const float* b2    = (const float*)d_in[20];

  float* out       = (float*)d_out;
  float* out_xp    = out;
  float* out_mem   = out + (size_t)T_LEN * BATCH * HDIM;
  float* out_probs = out_mem + (size_t)T_LEN * BATCH * NS * HDIM;
  float* ws        = (float*)d_ws;

  hipLaunchKernelGGL(init_ctrl, dim3(8), dim3(256), 0, stream, (int*)d_ws);
  hipLaunchKernelGGL(xp_kernel, dim3(1024), dim3(256), 0, stream, X, Wp, bp, lns, lnb, out_xp);
  hipLaunchKernelGGL(omr_main, dim3(NBLK), dim3(NTHR), 0, stream,
                     out_xp, Wq, bq, lnqs, lnqb, Wk, bk, lnks, lnkb, Wbeta, bbeta,
                     W1, b1, W2, b2, lns, lnb, out_mem, out_probs, ws);
}

// Round 2
// 39820.648 us; speedup vs baseline: 2.2062x; 2.2062x over previous
//
#include <hip/hip_runtime.h>
#include <math.h>

#define T_LEN 128
#define BATCH 64
#define IND   512
#define HDIM  256
#define NS    8
#define H4    1024
#define NTHR  512

// ws float layout: first 512 floats reserved as int flags (cluster rg uses ints [rg*128, rg*128+64))
#define WS_BASE  512
#define CLSZ     102400
#define OFF_QPRE 0
#define OFF_KPRE 4096
#define OFF_MN   36864
#define OFF_Z1   69632
#define OFF_Z2   86016
// total = 512 + 4*102400 = 410112 floats = 1.64 MB

// ---------------- per-cluster barrier: 64 blocks, flag-array + single fences ----------------
__device__ __forceinline__ void cbar(int* flags, int cg, int phase) {
  __syncthreads();                 // drains vmcnt: all block stores complete to L2
  if (threadIdx.x < 64) {
    if (threadIdx.x == 0) {
      __builtin_amdgcn_fence(__ATOMIC_RELEASE, "agent");   // L2 writeback once per barrier
      __hip_atomic_store(flags + cg, phase, __ATOMIC_RELAXED, __HIP_MEMORY_SCOPE_AGENT);
    }
    int v;
    do {
      v = __hip_atomic_load(flags + threadIdx.x, __ATOMIC_RELAXED, __HIP_MEMORY_SCOPE_AGENT);
    } while (__any(v < phase));
    __builtin_amdgcn_fence(__ATOMIC_ACQUIRE, "agent");     // L1/L2 invalidate once per barrier
  }
  __syncthreads();
}

extern "C" __global__ void init_ctrl(int* ctrl) {
  int t = blockIdx.x * blockDim.x + threadIdx.x;
  if (t < 512) ctrl[t] = 0;
}

// ---------------- Xp = tanh(LN(X @ W_proj + b)) ----------------
extern "C" __global__ __launch_bounds__(256) void xp_kernel(
    const float* __restrict__ X, const float* __restrict__ Wp, const float* __restrict__ bp,
    const float* __restrict__ lns, const float* __restrict__ lnb, float* __restrict__ out_xp)
{
  __shared__ float Xs[8 * IND];
  __shared__ float Ys[8 * HDIM];
  const int tid = threadIdx.x;
  const size_t base = (size_t)blockIdx.x * 8;
  const float* Xb = X + base * IND;
  for (int e = tid; e < 8 * IND / 4; e += 256) ((float4*)Xs)[e] = ((const float4*)Xb)[e];
  __syncthreads();
  float acc[8];
#pragma unroll
  for (int r = 0; r < 8; ++r) acc[r] = 0.f;
  for (int k = 0; k < IND; ++k) {
    float wv = Wp[k * HDIM + tid];
#pragma unroll
    for (int r = 0; r < 8; ++r) acc[r] += Xs[r * IND + k] * wv;
  }
  float bpv = bp[tid];
#pragma unroll
  for (int r = 0; r < 8; ++r) Ys[r * HDIM + tid] = acc[r] + bpv;
  __syncthreads();
  int w = tid >> 6, lane = tid & 63;
  for (int rr = 0; rr < 2; ++rr) {
    int r = w * 2 + rr;
    float v[4]; float s1 = 0.f, s2 = 0.f;
#pragma unroll
    for (int e = 0; e < 4; ++e) { v[e] = Ys[r * HDIM + lane + 64 * e]; s1 += v[e]; s2 += v[e] * v[e]; }
#pragma unroll
    for (int off = 32; off > 0; off >>= 1) { s1 += __shfl_xor(s1, off, 64); s2 += __shfl_xor(s2, off, 64); }
    float m = s1 / 256.f;
    float iv = rsqrtf(s2 / 256.f - m * m + 1e-5f);
#pragma unroll
    for (int e = 0; e < 4; ++e) {
      int hd = lane + 64 * e;
      out_xp[(base + r) * HDIM + hd] = tanhf((v[e] - m) * iv * lns[hd] + lnb[hd]);
    }
  }
}

// ---------------- main recurrent kernel: 4 clusters x 64 blocks ----------------
extern "C" __global__ __launch_bounds__(NTHR, 1) void omr_main(
    const float* __restrict__ Xp,
    const float* __restrict__ Wq, const float* __restrict__ bq,
    const float* __restrict__ lnqs, const float* __restrict__ lnqb,
    const float* __restrict__ Wk, const float* __restrict__ bk,
    const float* __restrict__ lnks, const float* __restrict__ lnkb,
    const float* __restrict__ Wbeta, const float* __restrict__ bbeta,
    const float* __restrict__ W1, const float* __restrict__ b1,
    const float* __restrict__ W2, const float* __restrict__ b2,
    const float* __restrict__ lns, const float* __restrict__ lnb,
    float* __restrict__ mem_out, float* __restrict__ probs_out, float* __restrict__ ws)
{
  const int tid = threadIdx.x;
  const int cg = blockIdx.x & 63;   // column group (64 per cluster)
  const int rg = blockIdx.x >> 6;   // cluster / row group (4 clusters x 16 rows)
  const int ZC0 = cg * 16;          // z1/z2 columns owned
  const int QC0 = cg * 4;           // q/k/hd columns owned

  // LDS (~157 KB, 1 block/CU)
  __shared__ float W1s[16 * 516];     // [c][k] padded, W1 col slice
  __shared__ float W2s[16 * 1028];    // [c][k] padded
  __shared__ float hlocS[16 * 260];   // current h (padded rows)
  __shared__ float xpS[16 * 256];     // Xp[t] rows
  __shared__ float scratch[4096];     // union: qln (P1) / split-K partials (Z) / Wq,Wk staging (S1a)
  __shared__ float LNS_[256], LNB_[256], LNQS_[256], LNQB_[256], LNKS_[256], LNKB_[256], Wbs[256];
  __shared__ float b1s[16], b2s[16], bqS[4], bkS[4];
  __shared__ float cpS[128], rcpS[128], betaS[128], statS[32];
  __shared__ float bbetaS;

  float* cl      = ws + WS_BASE + (size_t)rg * CLSZ;
  float* QPREws  = cl + OFF_QPRE;   // [16][256]
  float* KPREws  = cl + OFF_KPRE;   // [128][256]
  float* MNws    = cl + OFF_MN;     // [16][8][256]
  float* Z1ws    = cl + OFF_Z1;     // [16][1024]
  float* Z2ws    = cl + OFF_Z2;     // [16][1024]
  int*   flags   = (int*)ws + rg * 128;

  // ---- load resident weights ----
  for (int e = tid; e < 16 * 512; e += NTHR) { int k = e >> 4, c = e & 15; W1s[c * 516 + k] = W1[(size_t)k * H4 + ZC0 + c]; }
  for (int e = tid; e < 16 * 1024; e += NTHR) { int k = e >> 4, c = e & 15; W2s[c * 1028 + k] = W2[(size_t)k * H4 + ZC0 + c]; }
  if (tid < 256) {
    LNS_[tid] = lns[tid];  LNB_[tid] = lnb[tid];
    LNQS_[tid] = lnqs[tid]; LNQB_[tid] = lnqb[tid];
    LNKS_[tid] = lnks[tid]; LNKB_[tid] = lnkb[tid];
    Wbs[tid] = Wbeta[tid];
  }
  if (tid < 16) { b1s[tid] = b1[ZC0 + tid]; b2s[tid] = b2[ZC0 + tid]; }
  if (tid < 4)  { bqS[tid] = bq[QC0 + tid]; bkS[tid] = bk[QC0 + tid]; }
  if (tid == 0) bbetaS = bbeta[0];

  int ph = 0;

  // ================= t = 0 init + S1a for t=1 =================
  {
    // M = 0 (own hd slice); mem_out[0][b][i][:] = Xp[0][b][:]; probs[0] = 0
    int r = tid >> 5, s = (tid >> 2) & 7, cq = tid & 3;
    int hd = QC0 + cq;
    int b = rg * 16 + r;
    MNws[(r * NS + s) * HDIM + hd] = 0.f;
    mem_out[((size_t)b * NS + s) * HDIM + hd] = Xp[(size_t)b * HDIM + hd];
    if (cg < 16 && tid < NS) probs_out[(size_t)(rg * 16 + cg) * NS + tid] = 0.f;

    // stage Wq/Wk column slices
    for (int e = tid; e < 2048; e += NTHR) {
      int w2 = e >> 10, rem = e & 1023, c = rem >> 8, k = rem & 255;
      const float* W = w2 ? Wk : Wq;
      scratch[e] = W[k * HDIM + QC0 + c];
    }
    __syncthreads();
    // qpre(t=1) = Xp[1]@Wq ; kpre(t=1): cM(0) rows identical across slots = Xp[0]
    for (int o = tid; o < 128; o += NTHR) {
      int r2 = (o & 63) >> 2, c = o & 3;
      bool isq = o < 64;
      const float* A = Xp + ((size_t)(isq ? 1 : 0) * BATCH + rg * 16 + r2) * HDIM;
      const float* Wc = scratch + (isq ? 0 : 1024) + c * HDIM;
      float a0 = 0, a1 = 0, a2 = 0, a3 = 0;
      for (int k = 0; k < HDIM; k += 4) {
        float4 a = *(const float4*)(A + k);
        float4 w4 = *(float4*)(Wc + k);
        a0 += a.x * w4.x; a1 += a.y * w4.y; a2 += a.z * w4.z; a3 += a.w * w4.w;
      }
      float acc = (a0 + a1) + (a2 + a3);
      if (isq) QPREws[r2 * HDIM + QC0 + c] = acc + bqS[c];
      else {
        acc += bkS[c];
        for (int s2 = 0; s2 < NS; ++s2) KPREws[(r2 * NS + s2) * HDIM + QC0 + c] = acc;
      }
    }
  }
  cbar(flags, cg, ++ph);

  // ================= time loop =================
  for (int t = 1; t < T_LEN; ++t) {
    const size_t tb = (size_t)t * BATCH;

    // ---------- P1: LN(q), LN(k)+beta, softmax/p/cp/rcp (redundant), Mn slice, hloc=Xp[t] ----------
    {
      // q layernorm -> scratch[r*256+hd]
      int r = tid >> 5, u = tid & 31, hd = u * 8;
      const float* q = QPREws + r * HDIM + hd;
      float4 a = *(const float4*)q, bB = *(const float4*)(q + 4);
      float s1 = a.x + a.y + a.z + a.w + bB.x + bB.y + bB.z + bB.w;
      float s2 = a.x * a.x + a.y * a.y + a.z * a.z + a.w * a.w + bB.x * bB.x + bB.y * bB.y + bB.z * bB.z + bB.w * bB.w;
#pragma unroll
      for (int m = 1; m < 32; m <<= 1) { s1 += __shfl_xor(s1, m, 64); s2 += __shfl_xor(s2, m, 64); }
      float mean = s1 * (1.f / 256.f);
      float inv = rsqrtf(s2 * (1.f / 256.f) - mean * mean + 1e-5f);
      float qv[8] = {a.x, a.y, a.z, a.w, bB.x, bB.y, bB.z, bB.w};
#pragma unroll
      for (int j = 0; j < 8; ++j)
        scratch[r * HDIM + hd + j] = (qv[j] - mean) * inv * LNQS_[hd + j] + LNQB_[hd + j];
    }
    __syncthreads();
    {
      // k layernorm + beta (4 threads per k-row)
      int kr = tid >> 2, u4 = tid & 3;
      int r = kr >> 3;
      const float* kp = KPREws + kr * HDIM + u4 * 64;
      float kv[16][4];
      float s1 = 0.f, s2 = 0.f;
#pragma unroll
      for (int e = 0; e < 16; ++e) {
        float4 a = *(const float4*)(kp + e * 4);
        kv[e][0] = a.x; kv[e][1] = a.y; kv[e][2] = a.z; kv[e][3] = a.w;
        s1 += a.x + a.y + a.z + a.w;
        s2 += a.x * a.x + a.y * a.y + a.z * a.z + a.w * a.w;
      }
      s1 += __shfl_xor(s1, 1, 64); s1 += __shfl_xor(s1, 2, 64);
      s2 += __shfl_xor(s2, 1, 64); s2 += __shfl_xor(s2, 2, 64);
      float mean = s1 * (1.f / 256.f);
      float inv = rsqrtf(s2 * (1.f / 256.f) - mean * mean + 1e-5f);
      float dot = 0.f;
#pragma unroll
      for (int e = 0; e < 16; ++e) {
#pragma unroll
        for (int j = 0; j < 4; ++j) {
          int hd = u4 * 64 + e * 4 + j;
          float kl = (kv[e][j] - mean) * inv * LNKS_[hd] + LNKB_[hd];
          float rv = fmaxf(scratch[r * HDIM + hd] + kl, 0.f);
          dot += rv * Wbs[hd];
        }
      }
      dot += __shfl_xor(dot, 1, 64); dot += __shfl_xor(dot, 2, 64);
      if (u4 == 0) betaS[kr] = (dot + bbetaS) * 0.0625f;
    }
    __syncthreads();
    if (tid < 16) {
      // per-row softmax + mask + p/cp/rcp (redundant in every block)
      int r = tid, b = rg * 16 + r;
      float pp[8], pcp[8], run = 0.f;
#pragma unroll
      for (int s = 0; s < NS; ++s) {
        pp[s] = probs_out[((size_t)(t - 1) * BATCH + b) * NS + s];
        run += pp[s]; pcp[s] = run;
      }
      float bmax = betaS[r * 8];
#pragma unroll
      for (int s = 1; s < NS; ++s) bmax = fmaxf(bmax, betaS[r * 8 + s]);
      float xm[8], ssum = 0.f;
#pragma unroll
      for (int s = 0; s < NS; ++s) {
        float mi;
        if (s < 7) { float cv = pcp[s + 1]; mi = (cv < 1e-5f) ? 0.f : cv; }
        else mi = 1.f;
        float xv = expf(betaS[r * 8 + s] - bmax);
        xm[s] = xv * mi; ssum += fabsf(xm[s]);
      }
      float denom = fmaxf(ssum, 1e-12f);
      float run2 = 0.f, pn[8];
#pragma unroll
      for (int s = 0; s < NS; ++s) {
        pn[s] = xm[s] / denom; run2 += pn[s];
        cpS[r * 8 + s] = run2;
        if (cg == r) probs_out[(tb + b) * NS + s] = pn[s];
      }
      float run3 = 0.f;
#pragma unroll
      for (int s = NS - 1; s >= 0; --s) { run3 += pn[s]; rcpS[r * 8 + s] = run3; }
    }
    __syncthreads();
    {
      // Mn update (own 4-hd slice, all 16 rows x 8 slots)
      int r = tid >> 5, s = (tid >> 2) & 7, cq = tid & 3;
      int hd = QC0 + cq, b = rg * 16 + r;
      int idx = (r * NS + s) * HDIM + hd;
      float rc = rcpS[r * 8 + s];
      float mold = MNws[idx];
      float cm = mem_out[(((size_t)(t - 1) * BATCH + b) * NS + s) * HDIM + hd];
      MNws[idx] = mold * (1.f - rc) + cm * rc;
    }
    {
      // hloc = xp = Xp[t]
      int r = tid >> 5, u = tid & 31, hd = u * 8;
      const float* xp = Xp + (tb + rg * 16 + r) * HDIM + hd;
      float4 a = *(const float4*)xp, bB = *(const float4*)(xp + 4);
      *(float4*)&xpS[r * HDIM + hd] = a;     *(float4*)&xpS[r * HDIM + hd + 4] = bB;
      *(float4*)&hlocS[r * 260 + hd] = a;    *(float4*)&hlocS[r * 260 + hd + 4] = bB;
    }
    cbar(flags, cg, ++ph);

    // ---------- Z1(0) ----------
    {
      const int w = tid >> 6, lane = tid & 63;
      const int c = lane & 15, rb = ((lane >> 4) & 3) * 4;
      const int kb = w * 64;
      float acc0 = 0, acc1 = 0, acc2 = 0, acc3 = 0;
      if (w < 4) {
        for (int kk = 0; kk < 64; kk += 4) {
          const int k = kb + kk;
          float4 w4 = *(float4*)&W1s[c * 516 + k];
          float4 a0 = *(float4*)&hlocS[(rb + 0) * 260 + k];
          float4 a1 = *(float4*)&hlocS[(rb + 1) * 260 + k];
          float4 a2 = *(float4*)&hlocS[(rb + 2) * 260 + k];
          float4 a3 = *(float4*)&hlocS[(rb + 3) * 260 + k];
          acc0 += a0.x * w4.x + a0.y * w4.y + a0.z * w4.z + a0.w * w4.w;
          acc1 += a1.x * w4.x + a1.y * w4.y + a1.z * w4.z + a1.w * w4.w;
          acc2 += a2.x * w4.x + a2.y * w4.y + a2.z * w4.z + a2.w * w4.w;
          acc3 += a3.x * w4.x + a3.y * w4.y + a3.z * w4.z + a3.w * w4.w;
        }
      } else {
        for (int kk = 0; kk < 64; kk += 4) {
          const int k = kb + kk, km = k - 256;
          float4 w4 = *(float4*)&W1s[c * 516 + k];
          float4 a0 = *(const float4*)(MNws + ((rb + 0) * NS + 0) * HDIM + km);
          float4 a1 = *(const float4*)(MNws + ((rb + 1) * NS + 0) * HDIM + km);
          float4 a2 = *(const float4*)(MNws + ((rb + 2) * NS + 0) * HDIM + km);
          float4 a3 = *(const float4*)(MNws + ((rb + 3) * NS + 0) * HDIM + km);
          acc0 += a0.x * w4.x + a0.y * w4.y + a0.z * w4.z + a0.w * w4.w;
          acc1 += a1.x * w4.x + a1.y * w4.y + a1.z * w4.z + a1.w * w4.w;
          acc2 += a2.x * w4.x + a2.y * w4.y + a2.z * w4.z + a2.w * w4.w;
          acc3 += a3.x * w4.x + a3.y * w4.y + a3.z * w4.z + a3.w * w4.w;
        }
      }
      scratch[w * 256 + (rb + 0) * 16 + c] = acc0;
      scratch[w * 256 + (rb + 1) * 16 + c] = acc1;
      scratch[w * 256 + (rb + 2) * 16 + c] = acc2;
      scratch[w * 256 + (rb + 3) * 16 + c] = acc3;
    }
    __syncthreads();
    if (tid < 256) {
      float v = 0.f;
#pragma unroll
      for (int w = 0; w < 8; ++w) v += scratch[w * 256 + tid];
      int r = tid >> 4, c = tid & 15;
      Z1ws[r * H4 + ZC0 + c] = fmaxf(v + b1s[c], 0.f);
    }
    cbar(flags, cg, ++ph);

    // ---------- cells ----------
    for (int ci = 0; ci < NS; ++ci) {
      // ---- Z2(ci): z2 = relu_z1 @ W2 + b2 ----
      {
        const int w = tid >> 6, lane = tid & 63;
        const int c = lane & 15, rb = ((lane >> 4) & 3) * 4;
        const int kb = w * 128;
        float acc0 = 0, acc1 = 0, acc2 = 0, acc3 = 0;
        for (int kk = 0; kk < 128; kk += 4) {
          const int k = kb + kk;
          float4 w4 = *(float4*)&W2s[c * 1028 + k];
          float4 a0 = *(const float4*)(Z1ws + (rb + 0) * H4 + k);
          float4 a1 = *(const float4*)(Z1ws + (rb + 1) * H4 + k);
          float4 a2 = *(const float4*)(Z1ws + (rb + 2) * H4 + k);
          float4 a3 = *(const float4*)(Z1ws + (rb + 3) * H4 + k);
          acc0 += a0.x * w4.x + a0.y * w4.y + a0.z * w4.z + a0.w * w4.w;
          acc1 += a1.x * w4.x + a1.y * w4.y + a1.z * w4.z + a1.w * w4.w;
          acc2 += a2.x * w4.x + a2.y * w4.y + a2.z * w4.z + a2.w * w4.w;
          acc3 += a3.x * w4.x + a3.y * w4.y + a3.z * w4.z + a3.w * w4.w;
        }
        __syncthreads();   // scratch free from previous use
        scratch[(tid >> 6) * 256 + (rb + 0) * 16 + c] = acc0;
        scratch[(tid >> 6) * 256 + (rb + 1) * 16 + c] = acc1;
        scratch[(tid >> 6) * 256 + (rb + 2) * 16 + c] = acc2;
        scratch[(tid >> 6) * 256 + (rb + 3) * 16 + c] = acc3;
      }
      __syncthreads();
      if (tid < 256) {
        float v = 0.f;
#pragma unroll
        for (int w = 0; w < 8; ++w) v += scratch[w * 256 + tid];
        int r = tid >> 4, c = tid & 15;
        Z2ws[r * H4 + ZC0 + c] = v + b2s[c];
      }
      cbar(flags, cg, ++ph);

      // ---- H(ci): gates + LN(c)+tanh + h update (redundant), write mem slice; then Z1(ci+1) or S1a ----
      {
        // LN stats over z2[:, 768:1024]
        int r = tid >> 5, u = tid & 31, hd = u * 8;
        const float* z = Z2ws + r * H4 + 768 + hd;
        float4 a = *(const float4*)z, bB = *(const float4*)(z + 4);
        float s1 = a.x + a.y + a.z + a.w + bB.x + bB.y + bB.z + bB.w;
        float s2 = a.x * a.x + a.y * a.y + a.z * a.z + a.w * a.w + bB.x * bB.x + bB.y * bB.y + bB.z * bB.z + bB.w * bB.w;
#pragma unroll
        for (int m = 1; m < 32; m <<= 1) { s1 += __shfl_xor(s1, m, 64); s2 += __shfl_xor(s2, m, 64); }
        if (u == 0) {
          float mean = s1 * (1.f / 256.f);
          statS[r * 2] = mean;
          statS[r * 2 + 1] = rsqrtf(s2 * (1.f / 256.f) - mean * mean + 1e-5f);
        }
      }
      __syncthreads();
      {
        int r = tid >> 5, u = tid & 31, hd0 = u * 8;
        int b = rg * 16 + r;
        float g[24], cc[8], hi[8];
        {
          const float* zr = Z2ws + r * H4 + hd0 * 3;
#pragma unroll
          for (int e = 0; e < 6; ++e) *(float4*)&g[e * 4] = *(const float4*)(zr + e * 4);
          const float* zc = Z2ws + r * H4 + 768 + hd0;
          *(float4*)&cc[0] = *(const float4*)zc; *(float4*)&cc[4] = *(const float4*)(zc + 4);
          const float* mi = MNws + (r * NS + ci) * HDIM + hd0;
          *(float4*)&hi[0] = *(const float4*)mi; *(float4*)&hi[4] = *(const float4*)(mi + 4);
        }
        float mean = statS[r * 2], inv = statS[r * 2 + 1];
        float cp = cpS[r * 8 + ci];
#pragma unroll
        for (int j = 0; j < 8; ++j) {
          int hd = hd0 + j;
          float z0 = g[3 * j], z1v = g[3 * j + 1], z2g = g[3 * j + 2];
          float gm = fmaxf(z0, fmaxf(z1v, z2g));
          float e0 = expf(z0 - gm), e1 = expf(z1v - gm), e2 = expf(z2g - gm);
          float gs = 1.f / (e0 + e1 + e2);
          float act = tanhf((cc[j] - mean) * inv * LNS_[hd] + LNB_[hd]);
          float vi = hlocS[r * 260 + hd];
          float hc = (e0 * vi + e1 * hi[j] + e2 * act) * gs;
          float hn = xpS[r * HDIM + hd] * (1.f - cp) + hc * cp;
          hlocS[r * 260 + hd] = hn;
          if (hd >= QC0 && hd < QC0 + 4)
            mem_out[((tb + b) * NS + ci) * HDIM + hd] = hn;
        }
      }
      __syncthreads();

      if (ci < 7) {
        // ---- Z1(ci+1) ----
        const int i2 = ci + 1;
        const int w = tid >> 6, lane = tid & 63;
        const int c = lane & 15, rb = ((lane >> 4) & 3) * 4;
        const int kb = w * 64;
        float acc0 = 0, acc1 = 0, acc2 = 0, acc3 = 0;
        if (w < 4) {
          for (int kk = 0; kk < 64; kk += 4) {
            const int k = kb + kk;
            float4 w4 = *(float4*)&W1s[c * 516 + k];
            float4 a0 = *(float4*)&hlocS[(rb + 0) * 260 + k];
            float4 a1 = *(float4*)&hlocS[(rb + 1) * 260 + k];
            float4 a2 = *(float4*)&hlocS[(rb + 2) * 260 + k];
            float4 a3 = *(float4*)&hlocS[(rb + 3) * 260 + k];
            acc0 += a0.x * w4.x + a0.y * w4.y + a0.z * w4.z + a0.w * w4.w;
            acc1 += a1.x * w4.x + a1.y * w4.y + a1.z * w4.z + a1.w * w4.w;
            acc2 += a2.x * w4.x + a2.y * w4.y + a2.z * w4.z + a2.w * w4.w;
            acc3 += a3.x * w4.x + a3.y * w4.y + a3.z * w4.z + a3.w * w4.w;
          }
        } else {
          for (int kk = 0; kk < 64; kk += 4) {
            const int k = kb + kk, km = k - 256;
            float4 w4 = *(float4*)&W1s[c * 516 + k];
            float4 a0 = *(const float4*)(MNws + ((rb + 0) * NS + i2) * HDIM + km);
            float4 a1 = *(const float4*)(MNws + ((rb + 1) * NS + i2) * HDIM + km);
            float4 a2 = *(const float4*)(MNws + ((rb + 2) * NS + i2) * HDIM + km);
            float4 a3 = *(const float4*)(MNws + ((rb + 3) * NS + i2) * HDIM + km);
            acc0 += a0.x * w4.x + a0.y * w4.y + a0.z * w4.z + a0.w * w4.w;
            acc1 += a1.x * w4.x + a1.y * w4.y + a1.z * w4.z + a1.w * w4.w;
            acc2 += a2.x * w4.x + a2.y * w4.y + a2.z * w4.z + a2.w * w4.w;
            acc3 += a3.x * w4.x + a3.y * w4.y + a3.z * w4.z + a3.w * w4.w;
          }
        }
        scratch[w * 256 + (rb + 0) * 16 + c] = acc0;
        scratch[w * 256 + (rb + 1) * 16 + c] = acc1;
        scratch[w * 256 + (rb + 2) * 16 + c] = acc2;
        scratch[w * 256 + (rb + 3) * 16 + c] = acc3;
        __syncthreads();
        if (tid < 256) {
          float v = 0.f;
#pragma unroll
          for (int w2 = 0; w2 < 8; ++w2) v += scratch[w2 * 256 + tid];
          int r = tid >> 4, c2 = tid & 15;
          Z1ws[r * H4 + ZC0 + c2] = fmaxf(v + b1s[c2], 0.f);
        }
      } else if (t < T_LEN - 1) {
        // ---- S1a(t+1): qpre = Xp[t+1]@Wq ; kpre = cM(t)@Wk (slot 7 from hlocS) ----
        for (int e = tid; e < 2048; e += NTHR) {
          int w2 = e >> 10, rem = e & 1023, c = rem >> 8, k = rem & 255;
          const float* W = w2 ? Wk : Wq;
          scratch[e] = W[k * HDIM + QC0 + c];
        }
        __syncthreads();
        for (int o = tid; o < 576; o += NTHR) {
          float a0 = 0, a1 = 0, a2 = 0, a3 = 0;
          if (o < 64) {
            int r = o >> 2, c = o & 3;
            const float* A = Xp + ((size_t)(t + 1) * BATCH + rg * 16 + r) * HDIM;
            const float* Wc = scratch + c * HDIM;
            for (int k = 0; k < HDIM; k += 4) {
              float4 a = *(const float4*)(A + k);
              float4 w4 = *(float4*)(Wc + k);
              a0 += a.x * w4.x; a1 += a.y * w4.y; a2 += a.z * w4.z; a3 += a.w * w4.w;
            }
            QPREws[r * HDIM + QC0 + c] = (a0 + a1) + (a2 + a3) + bqS[c];
          } else {
            int kr = o - 64;
            int row = kr >> 2, c = kr & 3;
            int r = row >> 3, s = row & 7;
            const float* Wc = scratch + 1024 + c * HDIM;
            if (s < 7) {
              const float* A = mem_out + ((tb + rg * 16 + r) * NS + s) * HDIM;
              for (int k = 0; k < HDIM; k += 4) {
                float4 a = *(const float4*)(A + k);
                float4 w4 = *(float4*)(Wc + k);
                a0 += a.x * w4.x; a1 += a.y * w4.y; a2 += a.z * w4.z; a3 += a.w * w4.w;
              }
            } else {
              const float* A = &hlocS[r * 260];
              for (int k = 0; k < HDIM; k += 4) {
                float4 a = *(const float4*)(A + k);
                float4 w4 = *(float4*)(Wc + k);
                a0 += a.x * w4.x; a1 += a.y * w4.y; a2 += a.z * w4.z; a3 += a.w * w4.w;
              }
            }
            KPREws[row * HDIM + QC0 + c] = (a0 + a1) + (a2 + a3) + bkS[c];
          }
        }
      }
      cbar(flags, cg, ++ph);
    }
  }
}

extern "C" void kernel_launch(void* const* d_in, const int* in_sizes, int n_in,
                              void* d_out, int out_size, void* d_ws, size_t ws_size,
                              hipStream_t stream) {
  (void)in_sizes; (void)n_in; (void)out_size; (void)ws_size;
  const float* X     = (const float*)d_in[0];
  const float* Wp    = (const float*)d_in[3];
  const float* bp    = (const float*)d_in[4];
  const float* lns   = (const float*)d_in[5];
  const float* lnb   = (const float*)d_in[6];
  const float* Wq    = (const float*)d_in[7];
  const float* bq    = (const float*)d_in[8];
  const float* lnqs  = (const float*)d_in[9];
  const float* lnqb  = (const float*)d_in[10];
  const float* Wk    = (const float*)d_in[11];
  const float* bk    = (const float*)d_in[12];
  const float* lnks  = (const float*)d_in[13];
  const float* lnkb  = (const float*)d_in[14];
  const float* Wbeta = (const float*)d_in[15];
  const float* bbeta = (const float*)d_in[16];
  const float* W1    = (const float*)d_in[17];
  const float* b1    = (const float*)d_in[18];
  const float* W2    = (const float*)d_in[19];
  const float* b2    = (const float*)d_in[20];

  float* out       = (float*)d_out;
  float* out_xp    = out;
  float* out_mem   = out + (size_t)T_LEN * BATCH * HDIM;
  float* out_probs = out_mem + (size_t)T_LEN * BATCH * NS * HDIM;
  float* ws        = (float*)d_ws;

  hipLaunchKernelGGL(init_ctrl, dim3(2), dim3(256), 0, stream, (int*)d_ws);
  hipLaunchKernelGGL(xp_kernel, dim3(1024), dim3(256), 0, stream, X, Wp, bp, lns, lnb, out_xp);
  hipLaunchKernelGGL(omr_main, dim3(256), dim3(NTHR), 0, stream,
                     out_xp, Wq, bq, lnqs, lnqb, Wk, bk, lnks, lnkb, Wbeta, bbeta,
                     W1, b1, W2, b2, lns, lnb, out_mem, out_probs, ws);
}

// Round 3
// 33448.575 us; speedup vs baseline: 2.6264x; 1.1905x over previous
//
#include <hip/hip_runtime.h>
#include <math.h>

#define T_LEN 128
#define BATCH 64
#define IND   512
#define HDIM  256
#define NS    8
#define H4    1024
#define NTHR  512
typedef unsigned long long ull;

// ---- LLC-coherent (L2-bypass) accessors: agent-scope relaxed atomics ----
__device__ __forceinline__ float gload(const float* p) {
  return __hip_atomic_load(p, __ATOMIC_RELAXED, __HIP_MEMORY_SCOPE_AGENT);
}
__device__ __forceinline__ float2 gload2(const float* p) {
  ull v = __hip_atomic_load((const ull*)p, __ATOMIC_RELAXED, __HIP_MEMORY_SCOPE_AGENT);
  return __builtin_bit_cast(float2, v);
}
__device__ __forceinline__ void gstore(float* p, float v) {
  __hip_atomic_store(p, v, __ATOMIC_RELAXED, __HIP_MEMORY_SCOPE_AGENT);
}
__device__ __forceinline__ void gstore2(float* p, float a, float b) {
  float2 t = make_float2(a, b);
  __hip_atomic_store((ull*)p, __builtin_bit_cast(ull, t), __ATOMIC_RELAXED, __HIP_MEMORY_SCOPE_AGENT);
}

// ---- fence-free per-cluster barrier (64 blocks). All cross-block data uses
// bypass stores, so vmcnt(0) retirement == LLC visibility; no cache fences. ----
__device__ __forceinline__ void cbar(int* flags, int cg, int ph) {
  asm volatile("s_waitcnt vmcnt(0)" ::: "memory");
  __syncthreads();
  if (threadIdx.x == 0)
    __hip_atomic_store(flags + cg, ph, __ATOMIC_RELAXED, __HIP_MEMORY_SCOPE_AGENT);
  if (threadIdx.x < 64) {
    while (__hip_atomic_load(flags + threadIdx.x, __ATOMIC_RELAXED, __HIP_MEMORY_SCOPE_AGENT) < ph)
      __builtin_amdgcn_s_sleep(1);
  }
  __syncthreads();
}

extern "C" __global__ void init_ctrl(int* ctrl) {
  int t = blockIdx.x * blockDim.x + threadIdx.x;
  if (t < 512) ctrl[t] = 0;
}

// ---------------- Xp = tanh(LN(X @ W_proj + b)) ----------------
extern "C" __global__ __launch_bounds__(256) void xp_kernel(
    const float* __restrict__ X, const float* __restrict__ Wp, const float* __restrict__ bp,
    const float* __restrict__ lns, const float* __restrict__ lnb, float* __restrict__ out_xp)
{
  __shared__ float Xs[8 * IND];
  __shared__ float Ys[8 * HDIM];
  const int tid = threadIdx.x;
  const size_t base = (size_t)blockIdx.x * 8;
  const float* Xb = X + base * IND;
  for (int e = tid; e < 8 * IND / 4; e += 256) ((float4*)Xs)[e] = ((const float4*)Xb)[e];
  __syncthreads();
  float acc[8];
#pragma unroll
  for (int r = 0; r < 8; ++r) acc[r] = 0.f;
  for (int k = 0; k < IND; ++k) {
    float wv = Wp[k * HDIM + tid];
#pragma unroll
    for (int r = 0; r < 8; ++r) acc[r] += Xs[r * IND + k] * wv;
  }
  float bpv = bp[tid];
#pragma unroll
  for (int r = 0; r < 8; ++r) Ys[r * HDIM + tid] = acc[r] + bpv;
  __syncthreads();
  int w = tid >> 6, lane = tid & 63;
  for (int rr = 0; rr < 2; ++rr) {
    int r = w * 2 + rr;
    float v[4]; float s1 = 0.f, s2 = 0.f;
#pragma unroll
    for (int e = 0; e < 4; ++e) { v[e] = Ys[r * HDIM + lane + 64 * e]; s1 += v[e]; s2 += v[e] * v[e]; }
#pragma unroll
    for (int off = 32; off > 0; off >>= 1) { s1 += __shfl_xor(s1, off, 64); s2 += __shfl_xor(s2, off, 64); }
    float m = s1 / 256.f;
    float iv = rsqrtf(s2 / 256.f - m * m + 1e-5f);
#pragma unroll
    for (int e = 0; e < 4; ++e) {
      int hd = lane + 64 * e;
      out_xp[(base + r) * HDIM + hd] = tanhf((v[e] - m) * iv * lns[hd] + lnb[hd]);
    }
  }
}

// ws float layout: [0..511] int flags; per cluster rg (4 clusters):
//   base = 512 + rg*135168: QPRE[16*256]=0, KPRE[128*256]=4096, MB0=36864,
//   MB1=69632, Z1[16*1024]=102400, Z2=118784.  total 541,184 floats (2.2 MB)

// ---------------- main recurrent kernel: 4 clusters x 64 blocks ----------------
extern "C" __global__ __launch_bounds__(NTHR, 1) void omr_main(
    const float* __restrict__ Xp,
    const float* __restrict__ Wq, const float* __restrict__ bq,
    const float* __restrict__ lnqs, const float* __restrict__ lnqb,
    const float* __restrict__ Wk, const float* __restrict__ bk,
    const float* __restrict__ lnks, const float* __restrict__ lnkb,
    const float* __restrict__ Wbeta, const float* __restrict__ bbeta,
    const float* __restrict__ W1, const float* __restrict__ b1,
    const float* __restrict__ W2, const float* __restrict__ b2,
    const float* __restrict__ lns, const float* __restrict__ lnb,
    float* __restrict__ mem_out, float* __restrict__ probs_out, float* __restrict__ ws)
{
  const int tid = threadIdx.x;
  const int cg = blockIdx.x & 63;
  const int rg = blockIdx.x >> 6;
  const int ZC0 = cg * 16;          // z1/z2 cols owned
  const int QC0 = cg * 4;           // q/k/h cols owned
  const int w = tid >> 6, lane = tid & 63;
  const int tile = lane & 15, ksl = lane >> 4;
  const int rt = (tile >> 2) * 4, ct = (tile & 3) * 4;

  __shared__ float W1s[16 * 516];     // [c][k] W1 col slice (33 KB)
  __shared__ float W2s[16 * 1028];    // [c][k] W2 col slice (65.8 KB)
  __shared__ float hlocS[16 * 260];   // current h rows (padded)
  __shared__ float AstS[16 * 260];    // staging: A-chunks / qls / Wq-Wk
  __shared__ float redS[2048];        // split-K partials (float4/lane)
  __shared__ float LNS_[256], LNB_[256], LNQS_[256], LNQB_[256], LNKS_[256], LNKB_[256], Wbs[256];
  __shared__ float cpS[128], rcpS[128], betaS[128];
  __shared__ float b1s[16], b2s[16], bqS[4], bkS[4], bbetaS[1];

  float* cl    = ws + 512 + (size_t)rg * 135168;
  float* QPRE  = cl;
  float* KPRE  = cl + 4096;
  float* MB0   = cl + 36864;
  float* MB1   = cl + 69632;
  float* Z1c   = cl + 102400;
  float* Z2c   = cl + 118784;
  int*   flags = (int*)ws + rg * 64;

  for (int e = tid; e < 16 * 512; e += NTHR) { int k = e >> 4, c = e & 15; W1s[c * 516 + k] = W1[(size_t)k * H4 + ZC0 + c]; }
  for (int e = tid; e < 16 * 1024; e += NTHR) { int k = e >> 4, c = e & 15; W2s[c * 1028 + k] = W2[(size_t)k * H4 + ZC0 + c]; }
  if (tid < 256) {
    LNS_[tid] = lns[tid];  LNB_[tid] = lnb[tid];
    LNQS_[tid] = lnqs[tid]; LNQB_[tid] = lnqb[tid];
    LNKS_[tid] = lnks[tid]; LNKB_[tid] = lnkb[tid];
    Wbs[tid] = Wbeta[tid];
  }
  if (tid < 16) { b1s[tid] = b1[ZC0 + tid]; b2s[tid] = b2[ZC0 + tid]; }
  if (tid < 4)  { bqS[tid] = bq[QC0 + tid]; bkS[tid] = bk[QC0 + tid]; }
  if (tid == 0) bbetaS[0] = bbeta[0];

  // ---- t = 0 init ----
  {
    int e = cg * 512 + tid;           // 32768 per cluster
    gstore(MB0 + e, 0.f);
    int r = e >> 11, hd = e & 255;
    gstore(mem_out + (size_t)rg * 32768 + e, Xp[(size_t)(rg * 16 + r) * HDIM + hd]);
    if (cg == 0 && tid < 128) gstore(probs_out + rg * 128 + tid, 0.f);
  }
  // stage Wq/Wk slices, S1a for t=1 (cM(0) rows identical across slots = Xp[0])
  for (int e = tid; e < 2048; e += NTHR) {
    int s = e >> 10, rem = e & 1023, c = rem >> 8, k = rem & 255;
    AstS[e] = (s ? Wk : Wq)[k * HDIM + QC0 + c];
  }
  __syncthreads();
  for (int o = tid; o < 128; o += NTHR) {
    int r = (o & 63) >> 2, c = o & 3; bool isq = o < 64;
    const float* A = Xp + (size_t)((isq ? 1 : 0) * BATCH + rg * 16 + r) * HDIM;
    const float* Wc = AstS + (isq ? 0 : 1024) + c * 256;
    float a0 = 0, a1 = 0, a2 = 0, a3 = 0;
    for (int k = 0; k < 256; k += 4) {
      float4 a = *(const float4*)(A + k);
      a0 += a.x * Wc[k]; a1 += a.y * Wc[k + 1]; a2 += a.z * Wc[k + 2]; a3 += a.w * Wc[k + 3];
    }
    float acc = (a0 + a1) + (a2 + a3);
    if (isq) gstore(QPRE + r * HDIM + QC0 + c, acc + bqS[c]);
    else { float v = acc + bkS[c]; for (int s2 = 0; s2 < 8; ++s2) gstore(KPRE + (r * 8 + s2) * HDIM + QC0 + c, v); }
  }
  int ph = 0;
  cbar(flags, cg, ++ph);

  for (int t = 1; t < T_LEN; ++t) {
    const size_t tb = (size_t)t * BATCH;
    const float* memPrev = mem_out + (size_t)(t - 1) * BATCH * NS * HDIM;
    float* memCur = mem_out + tb * NS * HDIM;
    const float* probsPrev = probs_out + (size_t)(t - 1) * BATCH * NS;
    float* probsCur = probs_out + tb * NS;
    float* MbOld = ((t - 1) & 1) ? MB1 : MB0;
    float* MbNew = (t & 1) ? MB1 : MB0;
    const int r5 = tid >> 5, u5 = tid & 31, hd0 = u5 * 8;
    const int bglob = rg * 16 + r5;

    // ---- (1) q layernorm -> AstS ----
    {
      float q[8]; float s1 = 0.f, s2 = 0.f;
#pragma unroll
      for (int j = 0; j < 4; ++j) {
        float2 v = gload2(QPRE + r5 * HDIM + hd0 + 2 * j);
        q[2 * j] = v.x; q[2 * j + 1] = v.y;
        s1 += v.x + v.y; s2 += v.x * v.x + v.y * v.y;
      }
#pragma unroll
      for (int m = 1; m < 32; m <<= 1) { s1 += __shfl_xor(s1, m, 64); s2 += __shfl_xor(s2, m, 64); }
      float mean = s1 * (1.f / 256.f);
      float inv = rsqrtf(s2 * (1.f / 256.f) - mean * mean + 1e-5f);
#pragma unroll
      for (int j = 0; j < 8; ++j)
        AstS[r5 * 260 + hd0 + j] = (q[j] - mean) * inv * LNQS_[hd0 + j] + LNQB_[hd0 + j];
    }
    __syncthreads();
    // ---- (2) k layernorm + beta (redundant across blocks) ----
    {
      int kr = tid >> 2, u4 = tid & 3, r = kr >> 3;
      const float* kp = KPRE + kr * HDIM + u4 * 64;
      float kv[64]; float s1 = 0.f, s2 = 0.f;
#pragma unroll
      for (int e = 0; e < 32; ++e) {
        float2 v = gload2(kp + 2 * e);
        kv[2 * e] = v.x; kv[2 * e + 1] = v.y;
        s1 += v.x + v.y; s2 += v.x * v.x + v.y * v.y;
      }
      s1 += __shfl_xor(s1, 1, 64); s1 += __shfl_xor(s1, 2, 64);
      s2 += __shfl_xor(s2, 1, 64); s2 += __shfl_xor(s2, 2, 64);
      float mean = s1 * (1.f / 256.f);
      float inv = rsqrtf(s2 * (1.f / 256.f) - mean * mean + 1e-5f);
      float dot = 0.f;
#pragma unroll
      for (int e = 0; e < 64; ++e) {
        int hd = u4 * 64 + e;
        float kl = (kv[e] - mean) * inv * LNKS_[hd] + LNKB_[hd];
        float rv = fmaxf(AstS[r * 260 + hd] + kl, 0.f);
        dot += rv * Wbs[hd];
      }
      dot += __shfl_xor(dot, 1, 64); dot += __shfl_xor(dot, 2, 64);
      if (u4 == 0) betaS[kr] = (dot + bbetaS[0]) * 0.0625f;
    }
    __syncthreads();
    // ---- (3) softmax/p/cp/rcp (redundant) + hloc = Xp[t] ----
    if (tid < 16) {
      int r = tid, b = rg * 16 + r;
      float pp[8], pcp[8], run = 0.f;
#pragma unroll
      for (int s = 0; s < 8; s += 2) {
        float2 v = gload2(probsPrev + b * NS + s);
        pp[s] = v.x; pp[s + 1] = v.y;
      }
#pragma unroll
      for (int s = 0; s < 8; ++s) { run += pp[s]; pcp[s] = run; }
      float bmax = betaS[r * 8];
#pragma unroll
      for (int s = 1; s < 8; ++s) bmax = fmaxf(bmax, betaS[r * 8 + s]);
      float xm[8], ssum = 0.f;
#pragma unroll
      for (int s = 0; s < 8; ++s) {
        float mi;
        if (s < 7) { float cv = pcp[s + 1]; mi = (cv < 1e-5f) ? 0.f : cv; }
        else mi = 1.f;
        float xv = expf(betaS[r * 8 + s] - bmax);
        xm[s] = xv * mi; ssum += fabsf(xm[s]);
      }
      float denom = fmaxf(ssum, 1e-12f);
      float run2 = 0.f, pn[8];
#pragma unroll
      for (int s = 0; s < 8; ++s) {
        pn[s] = xm[s] / denom; run2 += pn[s];
        cpS[r * 8 + s] = run2;
        if (cg == r) gstore(probsCur + b * NS + s, pn[s]);
      }
      float run3 = 0.f;
#pragma unroll
      for (int s = 7; s >= 0; --s) { run3 += pn[s]; rcpS[r * 8 + s] = run3; }
    }
    {
      const float* xp = Xp + (tb + bglob) * HDIM + hd0;
      float4 a = *(const float4*)xp, bB = *(const float4*)(xp + 4);
      *(float4*)&hlocS[r5 * 260 + hd0] = a; *(float4*)&hlocS[r5 * 260 + hd0 + 4] = bB;
    }
    __syncthreads();
    // ---- (4) M-state owner update (slice) + Mn(slot 0) stage into AstS ----
    {
      int r = tid >> 5, s = (tid >> 2) & 7, cq = tid & 3;
      int hd = QC0 + cq;
      float rc = rcpS[r * 8 + s];
      int idx = (r * NS + s) * HDIM + hd;
      float mo = gload(MbOld + idx);
      float cm = gload(memPrev + ((size_t)(rg * 16 + r) * NS + s) * HDIM + hd);
      gstore(MbNew + idx, mo * (1.f - rc) + cm * rc);
    }
    for (int e = tid; e < 2048; e += NTHR) {
      int r = e >> 7, k2 = (e & 127) * 2;
      float rc = rcpS[r * 8 + 0];
      float2 mo = gload2(MbOld + (r * NS + 0) * HDIM + k2);
      float2 cm = gload2(memPrev + ((size_t)(rg * 16 + r) * NS + 0) * HDIM + k2);
      AstS[r * 260 + k2] = mo.x * (1.f - rc) + cm.x * rc;
      AstS[r * 260 + k2 + 1] = mo.y * (1.f - rc) + cm.y * rc;
    }
    __syncthreads();

    for (int ci = 0; ci < NS; ++ci) {
      // ---- Z1(ci): relu(cat(h, Mn_ci) @ W1 + b1) ; A: hlocS + AstS(Mn staged) ----
      {
        float acc[16];
#pragma unroll
        for (int e = 0; e < 16; ++e) acc[e] = 0.f;
        const float* Ap = (w < 4) ? hlocS : AstS;
        const int kb = w * 64 + ksl * 16;
        const int ka = (w < 4) ? kb : kb - 256;
#pragma unroll
        for (int kk = 0; kk < 16; kk += 4) {
          const int k = ka + kk, kw2 = kb + kk;
          float4 a0 = *(const float4*)&Ap[(rt + 0) * 260 + k];
          float4 a1 = *(const float4*)&Ap[(rt + 1) * 260 + k];
          float4 a2 = *(const float4*)&Ap[(rt + 2) * 260 + k];
          float4 a3 = *(const float4*)&Ap[(rt + 3) * 260 + k];
          float4 w0 = *(const float4*)&W1s[(ct + 0) * 516 + kw2];
          float4 w1 = *(const float4*)&W1s[(ct + 1) * 516 + kw2];
          float4 w2 = *(const float4*)&W1s[(ct + 2) * 516 + kw2];
          float4 w3 = *(const float4*)&W1s[(ct + 3) * 516 + kw2];
          acc[0] += a0.x * w0.x + a0.y * w0.y + a0.z * w0.z + a0.w * w0.w;
          acc[1] += a0.x * w1.x + a0.y * w1.y + a0.z * w1.z + a0.w * w1.w;
          acc[2] += a0.x * w2.x + a0.y * w2.y + a0.z * w2.z + a0.w * w2.w;
          acc[3] += a0.x * w3.x + a0.y * w3.y + a0.z * w3.z + a0.w * w3.w;
          acc[4] += a1.x * w0.x + a1.y * w0.y + a1.z * w0.z + a1.w * w0.w;
          acc[5] += a1.x * w1.x + a1.y * w1.y + a1.z * w1.z + a1.w * w1.w;
          acc[6] += a1.x * w2.x + a1.y * w2.y + a1.z * w2.z + a1.w * w2.w;
          acc[7] += a1.x * w3.x + a1.y * w3.y + a1.z * w3.z + a1.w * w3.w;
          acc[8] += a2.x * w0.x + a2.y * w0.y + a2.z * w0.z + a2.w * w0.w;
          acc[9] += a2.x * w1.x + a2.y * w1.y + a2.z * w1.z + a2.w * w1.w;
          acc[10] += a2.x * w2.x + a2.y * w2.y + a2.z * w2.z + a2.w * w2.w;
          acc[11] += a2.x * w3.x + a2.y * w3.y + a2.z * w3.z + a2.w * w3.w;
          acc[12] += a3.x * w0.x + a3.y * w0.y + a3.z * w0.z + a3.w * w0.w;
          acc[13] += a3.x * w1.x + a3.y * w1.y + a3.z * w1.z + a3.w * w1.w;
          acc[14] += a3.x * w2.x + a3.y * w2.y + a3.z * w2.z + a3.w * w2.w;
          acc[15] += a3.x * w3.x + a3.y * w3.y + a3.z * w3.z + a3.w * w3.w;
        }
#pragma unroll
        for (int e = 0; e < 16; ++e) { acc[e] += __shfl_xor(acc[e], 16, 64); acc[e] += __shfl_xor(acc[e], 32, 64); }
        if (lane < 16) {
#pragma unroll
          for (int q = 0; q < 4; ++q)
            *(float4*)&redS[w * 256 + lane * 16 + q * 4] = make_float4(acc[q * 4], acc[q * 4 + 1], acc[q * 4 + 2], acc[q * 4 + 3]);
        }
        __syncthreads();
        if (tid < 256) {
          int r = tid >> 4, c = tid & 15;
          int tl = (r >> 2) * 4 + (c >> 2), el = (r & 3) * 4 + (c & 3);
          float v = 0.f;
#pragma unroll
          for (int w2 = 0; w2 < 8; ++w2) v += redS[w2 * 256 + tl * 16 + el];
          gstore(Z1c + r * H4 + ZC0 + c, fmaxf(v + b1s[c], 0.f));
        }
      }
      cbar(flags, cg, ++ph);

      // ---- Z2(ci): z1 @ W2 + b2, A staged in 4 chunks of K=256 ----
      {
        float acc[16];
#pragma unroll
        for (int e = 0; e < 16; ++e) acc[e] = 0.f;
        for (int ch = 0; ch < 4; ++ch) {
          for (int e = tid; e < 2048; e += NTHR) {
            int r = e >> 7, k2 = (e & 127) * 2;
            float2 v = gload2(Z1c + r * H4 + ch * 256 + k2);
            AstS[r * 260 + k2] = v.x; AstS[r * 260 + k2 + 1] = v.y;
          }
          __syncthreads();
          const int kb = w * 32 + ksl * 8;
#pragma unroll
          for (int kk = 0; kk < 8; kk += 4) {
            const int k = kb + kk, kw2 = ch * 256 + kb + kk;
            float4 a0 = *(const float4*)&AstS[(rt + 0) * 260 + k];
            float4 a1 = *(const float4*)&AstS[(rt + 1) * 260 + k];
            float4 a2 = *(const float4*)&AstS[(rt + 2) * 260 + k];
            float4 a3 = *(const float4*)&AstS[(rt + 3) * 260 + k];
            float4 w0 = *(const float4*)&W2s[(ct + 0) * 1028 + kw2];
            float4 w1 = *(const float4*)&W2s[(ct + 1) * 1028 + kw2];
            float4 w2 = *(const float4*)&W2s[(ct + 2) * 1028 + kw2];
            float4 w3 = *(const float4*)&W2s[(ct + 3) * 1028 + kw2];
            acc[0] += a0.x * w0.x + a0.y * w0.y + a0.z * w0.z + a0.w * w0.w;
            acc[1] += a0.x * w1.x + a0.y * w1.y + a0.z * w1.z + a0.w * w1.w;
            acc[2] += a0.x * w2.x + a0.y * w2.y + a0.z * w2.z + a0.w * w2.w;
            acc[3] += a0.x * w3.x + a0.y * w3.y + a0.z * w3.z + a0.w * w3.w;
            acc[4] += a1.x * w0.x + a1.y * w0.y + a1.z * w0.z + a1.w * w0.w;
            acc[5] += a1.x * w1.x + a1.y * w1.y + a1.z * w1.z + a1.w * w1.w;
            acc[6] += a1.x * w2.x + a1.y * w2.y + a1.z * w2.z + a1.w * w2.w;
            acc[7] += a1.x * w3.x + a1.y * w3.y + a1.z * w3.z + a1.w * w3.w;
            acc[8] += a2.x * w0.x + a2.y * w0.y + a2.z * w0.z + a2.w * w0.w;
            acc[9] += a2.x * w1.x + a2.y * w1.y + a2.z * w1.z + a2.w * w1.w;
            acc[10] += a2.x * w2.x + a2.y * w2.y + a2.z * w2.z + a2.w * w2.w;
            acc[11] += a2.x * w3.x + a2.y * w3.y + a2.z * w3.z + a2.w * w3.w;
            acc[12] += a3.x * w0.x + a3.y * w0.y + a3.z * w0.z + a3.w * w0.w;
            acc[13] += a3.x * w1.x + a3.y * w1.y + a3.z * w1.z + a3.w * w1.w;
            acc[14] += a3.x * w2.x + a3.y * w2.y + a3.z * w2.z + a3.w * w2.w;
            acc[15] += a3.x * w3.x + a3.y * w3.y + a3.z * w3.z + a3.w * w3.w;
          }
          __syncthreads();
        }
#pragma unroll
        for (int e = 0; e < 16; ++e) { acc[e] += __shfl_xor(acc[e], 16, 64); acc[e] += __shfl_xor(acc[e], 32, 64); }
        if (lane < 16) {
#pragma unroll
          for (int q = 0; q < 4; ++q)
            *(float4*)&redS[w * 256 + lane * 16 + q * 4] = make_float4(acc[q * 4], acc[q * 4 + 1], acc[q * 4 + 2], acc[q * 4 + 3]);
        }
        __syncthreads();
        if (tid < 256) {
          int r = tid >> 4, c = tid & 15;
          int tl = (r >> 2) * 4 + (c >> 2), el = (r & 3) * 4 + (c & 3);
          float v = 0.f;
#pragma unroll
          for (int w2 = 0; w2 < 8; ++w2) v += redS[w2 * 256 + tl * 16 + el];
          gstore(Z2c + r * H4 + ZC0 + c, v + b2s[c]);
        }
      }
      cbar(flags, cg, ++ph);

      // ---- stage for next sub-step: Mn(ci+1) or Wq/Wk (into AstS) ----
      if (ci < 7) {
        for (int e = tid; e < 2048; e += NTHR) {
          int r = e >> 7, k2 = (e & 127) * 2;
          float rc = rcpS[r * 8 + ci + 1];
          float2 mo = gload2(MbOld + (r * NS + ci + 1) * HDIM + k2);
          float2 cm = gload2(memPrev + ((size_t)(rg * 16 + r) * NS + ci + 1) * HDIM + k2);
          AstS[r * 260 + k2] = mo.x * (1.f - rc) + cm.x * rc;
          AstS[r * 260 + k2 + 1] = mo.y * (1.f - rc) + cm.y * rc;
        }
      } else if (t < T_LEN - 1) {
        for (int e = tid; e < 2048; e += NTHR) {
          int s = e >> 10, rem = e & 1023, c = rem >> 8, k = rem & 255;
          AstS[e] = (s ? Wk : Wq)[k * HDIM + QC0 + c];
        }
      }

      // ---- H(ci): gates + LN(c)+tanh + h update (redundant full h) ----
      {
        const float* z2r = Z2c + r5 * H4;
        float cc[8]; float s1 = 0.f, s2 = 0.f;
#pragma unroll
        for (int j = 0; j < 4; ++j) {
          float2 v = gload2(z2r + 768 + hd0 + 2 * j);
          cc[2 * j] = v.x; cc[2 * j + 1] = v.y;
          s1 += v.x + v.y; s2 += v.x * v.x + v.y * v.y;
        }
#pragma unroll
        for (int m = 1; m < 32; m <<= 1) { s1 += __shfl_xor(s1, m, 64); s2 += __shfl_xor(s2, m, 64); }
        float mean = s1 * (1.f / 256.f);
        float inv = rsqrtf(s2 * (1.f / 256.f) - mean * mean + 1e-5f);
        float g[24];
#pragma unroll
        for (int j = 0; j < 12; ++j) {
          float2 v = gload2(z2r + hd0 * 3 + 2 * j);
          g[2 * j] = v.x; g[2 * j + 1] = v.y;
        }
        float rcI = rcpS[r5 * 8 + ci], cp = cpS[r5 * 8 + ci];
        float hi[8];
#pragma unroll
        for (int j = 0; j < 8; j += 2) {
          float2 mo = gload2(MbOld + (r5 * NS + ci) * HDIM + hd0 + j);
          float2 cm = gload2(memPrev + ((size_t)bglob * NS + ci) * HDIM + hd0 + j);
          hi[j] = mo.x * (1.f - rcI) + cm.x * rcI;
          hi[j + 1] = mo.y * (1.f - rcI) + cm.y * rcI;
        }
        float xpv[8];
        *(float4*)&xpv[0] = *(const float4*)&Xp[(tb + bglob) * HDIM + hd0];
        *(float4*)&xpv[4] = *(const float4*)&Xp[(tb + bglob) * HDIM + hd0 + 4];
        float hn[8];
#pragma unroll
        for (int j = 0; j < 8; ++j) {
          int hd = hd0 + j;
          float z0 = g[3 * j], z1v = g[3 * j + 1], z2g = g[3 * j + 2];
          float gm = fmaxf(z0, fmaxf(z1v, z2g));
          float e0 = expf(z0 - gm), e1 = expf(z1v - gm), e2 = expf(z2g - gm);
          float gs = 1.f / (e0 + e1 + e2);
          float act = tanhf((cc[j] - mean) * inv * LNS_[hd] + LNB_[hd]);
          float vi = hlocS[r5 * 260 + hd];
          float hc = (e0 * vi + e1 * hi[j] + e2 * act) * gs;
          hn[j] = xpv[j] * (1.f - cp) + hc * cp;
          hlocS[r5 * 260 + hd] = hn[j];
        }
        if (u5 == (QC0 >> 3)) {
          int o4 = QC0 & 4;
          float* mp = memCur + ((size_t)bglob * NS + ci) * HDIM + QC0;
          gstore2(mp, hn[o4], hn[o4 + 1]);
          gstore2(mp + 2, hn[o4 + 2], hn[o4 + 3]);
        }
      }
      __syncthreads();

      // ---- tail of cell: S1a(t+1) at ci==7 (Z1(ci+1) happens at loop top) ----
      if (ci == 7 && t < T_LEN - 1) {
        for (int o = tid; o < 576; o += NTHR) {
          if (o < 64) {
            int r = o >> 2, c = o & 3;
            const float* A = Xp + ((size_t)(t + 1) * BATCH + rg * 16 + r) * HDIM;
            const float* Wc = AstS + c * 256;
            float a0 = 0, a1 = 0, a2 = 0, a3 = 0;
            for (int k = 0; k < 256; k += 4) {
              float4 a = *(const float4*)(A + k);
              a0 += a.x * Wc[k]; a1 += a.y * Wc[k + 1]; a2 += a.z * Wc[k + 2]; a3 += a.w * Wc[k + 3];
            }
            gstore(QPRE + r * HDIM + QC0 + c, (a0 + a1) + (a2 + a3) + bqS[c]);
          } else {
            int kr = o - 64, row = kr >> 2, c = kr & 3, r = row >> 3, s = row & 7;
            const float* Wc = AstS + 1024 + c * 256;
            float d0 = 0.f, d1 = 0.f;
            if (s < 7) {
              const float* A = memCur + ((size_t)(rg * 16 + r) * NS + s) * HDIM;
              for (int k = 0; k < 256; k += 2) {
                float2 a = gload2(A + k);
                d0 += a.x * Wc[k]; d1 += a.y * Wc[k + 1];
              }
            } else {
              const float* A = &hlocS[r * 260];
              for (int k = 0; k < 256; k += 2) {
                d0 += A[k] * Wc[k]; d1 += A[k + 1] * Wc[k + 1];
              }
            }
            gstore(KPRE + row * HDIM + QC0 + c, d0 + d1 + bkS[c]);
          }
        }
      }
      if (ci < 7) { /* Z1(ci+1) runs at top of next iteration */ }
      cbar(flags, cg, ++ph);
    }
  }
}

extern "C" void kernel_launch(void* const* d_in, const int* in_sizes, int n_in,
                              void* d_out, int out_size, void* d_ws, size_t ws_size,
                              hipStream_t stream) {
  (void)in_sizes; (void)n_in; (void)out_size; (void)ws_size;
  const float* X     = (const float*)d_in[0];
  const float* Wp    = (const float*)d_in[3];
  const float* bp    = (const float*)d_in[4];
  const float* lns   = (const float*)d_in[5];
  const float* lnb   = (const float*)d_in[6];
  const float* Wq    = (const float*)d_in[7];
  const float* bq    = (const float*)d_in[8];
  const float* lnqs  = (const float*)d_in[9];
  const float* lnqb  = (const float*)d_in[10];
  const float* Wk    = (const float*)d_in[11];
  const float* bk    = (const float*)d_in[12];
  const float* lnks  = (const float*)d_in[13];
  const float* lnkb  = (const float*)d_in[14];
  const float* Wbeta = (const float*)d_in[15];
  const float* bbeta = (const float*)d_in[16];
  const float* W1    = (const float*)d_in[17];
  const float* b1    = (const float*)d_in[18];
  const float* W2    = (const float*)d_in[19];
  const float* b2    = (const float*)d_in[20];

  float* out       = (float*)d_out;
  float* out_xp    = out;
  float* out_mem   = out + (size_t)T_LEN * BATCH * HDIM;
  float* out_probs = out_mem + (size_t)T_LEN * BATCH * NS * HDIM;
  float* ws        = (float*)d_ws;

  hipLaunchKernelGGL(init_ctrl, dim3(2), dim3(256), 0, stream, (int*)d_ws);
  hipLaunchKernelGGL(xp_kernel, dim3(1024), dim3(256), 0, stream, X, Wp, bp, lns, lnb, out_xp);
  hipLaunchKernelGGL(omr_main, dim3(256), dim3(NTHR), 0, stream,
                     out_xp, Wq, bq, lnqs, lnqb, Wk, bk, lnks, lnkb, Wbeta, bbeta,
                     W1, b1, W2, b2, lns, lnb, out_mem, out_probs, ws);
}